// Round 10
// baseline (151.257 us; speedup 1.0000x reference)
//
#include <hip/hip_runtime.h>

// SINDy: out[65536,32] = Theta(z)[65536,6545] @ (Xi*Xi_mask)[6545,32]
// Round-10: FULLY-STATIC K-loop. The chunk schedule is compile-time known, so
// all meta/gather machinery (LDS mg tables, z-row LDS gathers, address math)
// is replaced by template-parameter indices: binary if-constexpr recursion
// (unroll refusal impossible - R1's failure mode eliminated by construction).
// Hot body per chunk: 2 static-subregister muls + 1 cndmask + 4 v_pk_mul_f32
// + 4 packs + 1 B load (static offset, 4-deep modulo buffer) + 1 MFMA.
// Zero LDS in the hot loop (LDS only for the 8 KB split-K combine).
// Split-K x2: block = 2 tiles x 2 k-halves (chunks [0,276) / [276,552)).
// MFMA 32x32x16_bf16 layouts (verified rounds 1-9):
//   A[m][k]: m=lane&31, k=(lane>>5)*8+jj
//   B[k][n]: n=lane&31, k=(lane>>5)*8+jj
//   C/D:     col=lane&31, row=(reg&3)+8*(reg>>2)+4*(lane>>5)

#define Z 32
#define ROWS 65536
#define NBLK (ROWS / 64)         // 1024 blocks: 2 tiles x 2 k-halves = 4 waves

#define NCHUNK 552               // quarters: 36 + 84 + 160 + 272
#define NGRAN (NCHUNK * 2)
#define KSPLIT 276

typedef short short8 __attribute__((ext_vector_type(8)));
typedef float f32x16 __attribute__((ext_vector_type(16)));
typedef float float2v __attribute__((ext_vector_type(2)));

struct Sched {
    short gi[NGRAN], gj[NGRAN];  // pair indices per granule (32 = z~=1 sentinel)
    char gq[NGRAN];              // quarter of granule
    short rt[NGRAN * 8];         // library row per (granule, jj), -1 = pad
    int nq[4];
};

constexpr Sched make_sched() {
    Sched s{};
    int tidx[32][32] = {}, pidx[32] = {};
    {
        int n = 0;
        for (int a = 0; a < 32; ++a)
            for (int b = a; b < 32; ++b) { tidx[a][b] = n; n += 32 - b; }
        for (int i = 0; i < 32; ++i) pidx[i] = i * 32 - i * (i - 1) / 2;
    }
    int g = 0;
    for (int q = 0; q < 4; ++q) {
        int g0 = g;
        // triples (a<=b): granule covers k in [8q,8q+8) for k>=b -> b>>3 <= q
        for (int b = 0; b < 32; ++b)
            if ((b >> 3) <= q)
                for (int a = 0; a <= b; ++a) { s.gi[g]=(short)a; s.gj[g]=(short)b; s.gq[g]=(char)q; ++g; }
        // pairs (b,32): theta = z_b*z_k, valid k<=b -> b>>3 >= q
        for (int b = 0; b < 32; ++b)
            if ((b >> 3) >= q) { s.gi[g]=(short)b; s.gj[g]=32; s.gq[g]=(char)q; ++g; }
        // linear: theta = z_k
        s.gi[g]=32; s.gj[g]=32; s.gq[g]=(char)q; ++g;
        // pad quarter to a multiple of 8 granules (4 chunks)
        while ((g - g0) & 7) { s.gi[g]=32; s.gj[g]=32; s.gq[g]=(char)q; ++g; }
        s.nq[q] = (g - g0) / 2;
    }
    // rebuild granule types for the rt table (same walk)
    g = 0;
    for (int q = 0; q < 4; ++q) {
        int g0 = g;
        for (int b = 0; b < 32; ++b)
            if ((b >> 3) <= q)
                for (int a = 0; a <= b; ++a) {
                    for (int jj = 0; jj < 8; ++jj) {
                        int k = 8 * q + jj;
                        s.rt[g*8+jj] = (short)((k >= b) ? 561 + tidx[a][b] + (k - b) : -1);
                    }
                    ++g;
                }
        for (int b = 0; b < 32; ++b)
            if ((b >> 3) >= q) {
                for (int jj = 0; jj < 8; ++jj) {
                    int k = 8 * q + jj;
                    s.rt[g*8+jj] = (short)((k <= b) ? 33 + pidx[k] + (b - k) : -1);
                }
                ++g;
            }
        for (int jj = 0; jj < 8; ++jj) s.rt[g*8+jj] = (short)(1 + 8*q + jj);
        ++g;
        while ((g - g0) & 7) {
            for (int jj = 0; jj < 8; ++jj) s.rt[g*8+jj] = -1;
            ++g;
        }
    }
    return s;
}
constexpr Sched S = make_sched();
static_assert(S.nq[0] == 36 && S.nq[1] == 84 && S.nq[2] == 160 && S.nq[3] == 272, "chunk counts");

__device__ __forceinline__ unsigned pack_bf16(float s0, float s1) {
#if __has_builtin(__builtin_amdgcn_cvt_pk_bf16_f32)
    return __builtin_bit_cast(unsigned, __builtin_amdgcn_cvt_pk_bf16_f32(s0, s1));
#else
    unsigned b0 = __builtin_bit_cast(unsigned, s0) + 0x8000u;
    unsigned b1 = __builtin_bit_cast(unsigned, s1) + 0x8000u;
    return __builtin_amdgcn_perm(b1, b0, 0x07060302u);   // lo16=s0, hi16=s1
#endif
}

// ---- prep (R7-proven): coalesced, block per 4 granules ----
__global__ void sindy_prep(const float* __restrict__ Xi,
                           const float* __restrict__ Xi_mask,
                           uint2* __restrict__ Bp2, size_t ws_size) {
    __shared__ unsigned short sh[8][32];
    const int tid = threadIdx.x;
    const int jj = tid >> 5, n = tid & 31;
#pragma unroll
    for (int pass = 0; pass < 4; ++pass) {
        int g = blockIdx.x * 4 + pass;
        int row = S.rt[g * 8 + jj];
        float f = 0.0f;
        if (row >= 0) f = Xi[row * Z + n] * Xi_mask[row * Z + n];
        unsigned u = __builtin_bit_cast(unsigned, f);
        sh[jj][n] = (unsigned short)((u + 0x7FFFu + ((u >> 16) & 1u)) >> 16);  // RNE
        __syncthreads();
        if (tid < 64) {
            int n2 = tid & 31, rep = tid >> 5;
            unsigned v0 = sh[4*rep+0][n2], v1 = sh[4*rep+1][n2];
            unsigned v2 = sh[4*rep+2][n2], v3 = sh[4*rep+3][n2];
            int c = g >> 1, h = g & 1;
            size_t idx = ((size_t)c * 64 + h * 32 + n2) * 2 + rep;
            if ((idx + 1) * 8 <= ws_size)
                Bp2[idx] = uint2{v0 | (v1 << 16), v2 | (v3 << 16)};
        }
        __syncthreads();
    }
}

// z~ row in registers: 17 aligned float2 pairs (v[16].x = 1.0 sentinel)
struct ZReg { float2v v[17]; };

// ---- fully-static K-loop: binary if-constexpr recursion over chunks ----
template<int C0, int C1>
__device__ __forceinline__ void kloop(const ZReg& Zr, bool hi,
                                      const uint4* __restrict__ bpl,
                                      uint4& b0, uint4& b1, uint4& b2, uint4& b3,
                                      f32x16& acc) {
    if constexpr (C1 - C0 > 1) {
        constexpr int M = C0 + (C1 - C0) / 2;
        kloop<C0, M>(Zr, hi, bpl, b0, b1, b2, b3, acc);
        kloop<M, C1>(Zr, hi, bpl, b0, b1, b2, b3, acc);
    } else {
        constexpr int C = C0;
        constexpr int i0 = S.gi[2*C],   j0 = S.gj[2*C];
        constexpr int i1 = S.gi[2*C+1], j1 = S.gj[2*C+1];
        constexpr int q  = S.gq[2*C];
        // pair products: static subregister reads, no gather
        float p0 = Zr.v[i0/2][i0%2] * Zr.v[j0/2][j0%2];
        float p1 = Zr.v[i1/2][i1%2] * Zr.v[j1/2][j1%2];
        float pp = hi ? p1 : p0;               // one v_cndmask
        float2v p2 = {pp, pp};
        union { unsigned u[4]; short8 sv; } a;
        float2v t0 = p2 * Zr.v[4*q+0]; a.u[0] = pack_bf16(t0.x, t0.y);
        float2v t1 = p2 * Zr.v[4*q+1]; a.u[1] = pack_bf16(t1.x, t1.y);
        float2v t2 = p2 * Zr.v[4*q+2]; a.u[2] = pack_bf16(t2.x, t2.y);
        float2v t3 = p2 * Zr.v[4*q+3]; a.u[3] = pack_bf16(t3.x, t3.y);
        // consume modulo buffer C%4
        union { uint4 v; short8 sv; } b;
        if constexpr (C % 4 == 0) b.v = b0;
        else if constexpr (C % 4 == 1) b.v = b1;
        else if constexpr (C % 4 == 2) b.v = b2;
        else b.v = b3;
        acc = __builtin_amdgcn_mfma_f32_32x32x16_bf16(a.sv, b.sv, acc, 0, 0, 0);
        // refill with chunk C+4 (static offset; skip past the table end)
        if constexpr (C + 4 < NCHUNK) {
            uint4 nb = bpl[(size_t)(C + 4) * 64];
            if constexpr (C % 4 == 0) b0 = nb;
            else if constexpr (C % 4 == 1) b1 = nb;
            else if constexpr (C % 4 == 2) b2 = nb;
            else b3 = nb;
        }
    }
}

// ---- main: block = 2 tiles x 2 k-halves; LDS only for the combine ----
__global__ __launch_bounds__(256, 4) void sindy_mfma(const float* __restrict__ z,
                                                     const float* __restrict__ Xi,
                                                     const float* __restrict__ Xi_mask,
                                                     const uint4* __restrict__ Bp,
                                                     float* __restrict__ out) {
    const int lane = threadIdx.x & 63;
    const int w = threadIdx.x >> 6;
    const int tib = w >> 1;          // tile-in-block 0/1
    const int kh = w & 1;            // k-half: 0 = [0,276), 1 = [276,552)
    const int m = lane & 31;
    const int half = lane >> 5;
    const long R = (long)blockIdx.x * 64 + tib * 32;

    __shared__ float cs[2][32][32];  // kh1 partials per tile (8 KB total LDS)

    // z~ row straight into registers (no LDS staging)
    ZReg Zr;
    const float4* z4 = (const float4*)(z + (R + m) * Z);
#pragma unroll
    for (int t = 0; t < 8; ++t) {
        float4 v = z4[t];
        Zr.v[2*t]   = float2v{v.x, v.y};
        Zr.v[2*t+1] = float2v{v.z, v.w};
    }
    Zr.v[16] = float2v{1.0f, 0.0f};   // z~[32] = 1.0 sentinel

    const bool hi = (half != 0);
    const uint4* bpl = Bp + lane;
    f32x16 acc = {};

    if (kh == 0) {
        uint4 b0 = bpl[0], b1 = bpl[64], b2 = bpl[128], b3 = bpl[192];
        kloop<0, KSPLIT>(Zr, hi, bpl, b0, b1, b2, b3, acc);
    } else {
        uint4 b0 = bpl[(size_t)KSPLIT * 64],       b1 = bpl[(size_t)(KSPLIT+1) * 64],
              b2 = bpl[(size_t)(KSPLIT+2) * 64],   b3 = bpl[(size_t)(KSPLIT+3) * 64];
        kloop<KSPLIT, NCHUNK>(Zr, hi, bpl, b0, b1, b2, b3, acc);
    }

    // combine: kh1 parks, kh0 reduces + stores
    if (kh == 1) {
#pragma unroll
        for (int r = 0; r < 16; ++r) {
            int row = (r & 3) + 8 * (r >> 2) + 4 * half;
            cs[tib][row][m] = acc[r];
        }
    }
    __syncthreads();
    if (kh == 0) {
        const float bias = Xi[m] * Xi_mask[m];   // library row 0 (ones), col n = m
        float* orow = out + R * Z;
#pragma unroll
        for (int r = 0; r < 16; ++r) {
            int row = (r & 3) + 8 * (r >> 2) + 4 * half;
            orow[row * Z + m] = acc[r] + cs[tib][row][m] + bias;
        }
    }
}

extern "C" void kernel_launch(void* const* d_in, const int* in_sizes, int n_in,
                              void* d_out, int out_size, void* d_ws, size_t ws_size,
                              hipStream_t stream) {
    const float* z       = (const float*)d_in[0];
    const float* Xi      = (const float*)d_in[1];
    const float* Xi_mask = (const float*)d_in[2];
    // d_in[3]=z_mean, d_in[4]=z_std: unused by the reference
    float* out = (float*)d_out;
    uint4* Bp  = (uint4*)d_ws;   // NCHUNK*64*16 = 565,248 bytes

    sindy_prep<<<NGRAN / 4, 256, 0, stream>>>(Xi, Xi_mask, (uint2*)d_ws, ws_size);
    sindy_mfma<<<NBLK, 256, 0, stream>>>(z, Xi, Xi_mask, Bp, out);
}